// Round 6
// baseline (139.907 us; speedup 1.0000x reference)
//
#include <hip/hip_runtime.h>
#include <math.h>

#define BB 4
#define NN 512
#define FIN 256
#define NH 8
#define FD 32
#define HF 256               // NH * FD
#define MASKH (-60000.0f)    // fp16-exact mask; exp underflow semantics same as -1e6
// leaky(x) = max(x, 0.21x) = CA*x + CB*|x|
#define CA 0.605f
#define CB 0.395f
#define IT 8                 // i-tile rows (R6: halved to double grid -> 8 blocks/CU)
#define ALIDX(j) ((j) + ((j) >> 4))  // skew: stride-16 reads hit distinct banks

typedef _Float16 h2_t __attribute__((ext_vector_type(2)));
union H2U { unsigned u; h2_t h; };

__device__ __forceinline__ h2_t pkrtz(float a, float b) {
  auto r = __builtin_amdgcn_cvt_pkrtz(a, b);
  union { decltype(r) f; h2_t h; } u;
  u.f = r;
  return u.h;
}

// x = gl2 + q2 (v_pk_add_f16); |x| (v_and 0x7fff7fff); acc += u2 . |x| (v_dot2)
__device__ __forceinline__ float acc2(unsigned g, h2_t q, h2_t u, float acc) {
  H2U v; v.u = g;
  h2_t s = v.h + q;
  H2U a; a.h = s; a.u &= 0x7fff7fffu;
  return __builtin_amdgcn_fdot2(a.h, u, acc, false);
}

// full 32-f score for one j: 16x acc2 on two chains
__device__ __forceinline__ float score32(const _Float16* gp_, const h2_t* qh,
                                         const h2_t* uh, float init) {
  const uint4* gp = (const uint4*)gp_;
  const uint4 g0 = gp[0], g1 = gp[1], g2 = gp[2], g3 = gp[3];
  float e0 = init, e1 = 0.f;
  e0 = acc2(g0.x, qh[0], uh[0], e0);
  e1 = acc2(g0.y, qh[1], uh[1], e1);
  e0 = acc2(g0.z, qh[2], uh[2], e0);
  e1 = acc2(g0.w, qh[3], uh[3], e1);
  e0 = acc2(g1.x, qh[4], uh[4], e0);
  e1 = acc2(g1.y, qh[5], uh[5], e1);
  e0 = acc2(g1.z, qh[6], uh[6], e0);
  e1 = acc2(g1.w, qh[7], uh[7], e1);
  e0 = acc2(g2.x, qh[8], uh[8], e0);
  e1 = acc2(g2.y, qh[9], uh[9], e1);
  e0 = acc2(g2.z, qh[10], uh[10], e0);
  e1 = acc2(g2.w, qh[11], uh[11], e1);
  e0 = acc2(g3.x, qh[12], uh[12], e0);
  e1 = acc2(g3.y, qh[13], uh[13], e1);
  e0 = acc2(g3.z, qh[14], uh[14], e0);
  e1 = acc2(g3.w, qh[15], uh[15], e1);
  return e0 + e1;
}

// ---------------------------------------------------------------------------
// Kernel 1: dual GEMM g = h @ W. y==0 -> gl fp16, y==1 -> gr fp32.
// ---------------------------------------------------------------------------
__global__ __launch_bounds__(256) void gemm_dual(
    const float* __restrict__ h, const float* __restrict__ Wl,
    const float* __restrict__ Wr, _Float16* __restrict__ glh,
    float* __restrict__ gr) {
  const int t = threadIdx.x;
  const int row0 = blockIdx.x * 8;
  const float* __restrict__ W = blockIdx.y ? Wr : Wl;

  float acc[8] = {0.f, 0.f, 0.f, 0.f, 0.f, 0.f, 0.f, 0.f};
  const float* Wp = W + t;
  const float* hp = h + (size_t)row0 * FIN;

#pragma unroll 2
  for (int k4 = 0; k4 < FIN / 4; ++k4) {
    float4 hv[8];
#pragma unroll
    for (int r = 0; r < 8; ++r)
      hv[r] = *(const float4*)(hp + r * FIN + 4 * k4);
#pragma unroll
    for (int kk = 0; kk < 4; ++kk) {
      const float w = Wp[(size_t)(4 * k4 + kk) * HF];
#pragma unroll
      for (int r = 0; r < 8; ++r) {
        const float hval = (kk == 0) ? hv[r].x
                         : (kk == 1) ? hv[r].y
                         : (kk == 2) ? hv[r].z : hv[r].w;
        acc[r] = fmaf(hval, w, acc[r]);
      }
    }
  }

  if (blockIdx.y == 0) {
    _Float16* gp = glh + (size_t)row0 * HF + t;
#pragma unroll
    for (int r = 0; r < 8; ++r) gp[(size_t)r * HF] = (_Float16)acc[r];
  } else {
    float* gp = gr + (size_t)row0 * HF + t;
#pragma unroll
    for (int r = 0; r < 8; ++r) gp[(size_t)r * HF] = acc[r];
  }
}

// ---------------------------------------------------------------------------
// Kernel 2: fused GATv2 attention. Block = (head hh, 8-row i-tile, batch b).
// Grid 2048 blocks -> 8 blocks/CU (32 waves, slot max). LDS ~15KB.
// e/p buffer packed fp16 (uint rows, odd stride 265 -> 2-way banks everywhere).
// ---------------------------------------------------------------------------
__global__ __launch_bounds__(256) void gat_attn(
    const _Float16* __restrict__ glh, const float* __restrict__ gr,
    const int* __restrict__ adj, const float* __restrict__ aw,
    float* __restrict__ out) {
  __shared__ unsigned e_s[IT][265];  // packed fp16 scores -> p; 8.5 KB
  __shared__ float Al_s[544];        // skew-indexed CA*(w.gl[j,:])
  __shared__ float q_s[IT][36];      // gr rows (fp32) of this i-tile
  __shared__ float w6_s[FD];         // CA * w
  __shared__ unsigned uh_s[16];      // CB * w packed fp16
  __shared__ unsigned w6h_s[16];     // CA * w packed fp16
  __shared__ float a_s[IT];          // CA * (w . gr[i,:])
  __shared__ float inv_l[IT];
  __shared__ float4 m_s[3][IT][8];   // phase-3 quarter partials; 3 KB

  const int t = threadIdx.x;
  const int hh = blockIdx.x;
  const int i0 = blockIdx.y * IT;
  const int b = blockIdx.z;

  if (t < FD) w6_s[t] = CA * aw[t];
  if (t < 16) {
    const float w0 = aw[2 * t], w1 = aw[2 * t + 1];
    H2U p0; p0.h = pkrtz(CB * w0, CB * w1);
    uh_s[t] = p0.u;
    H2U p1; p1.h = pkrtz(CA * w0, CA * w1);
    w6h_s[t] = p1.u;
  }
  if (t < 8 * IT) {  // stage q: IT x 32 floats
    const int ii = t >> 3, f4 = t & 7;
    *(float4*)&q_s[ii][f4 * 4] = *(const float4*)(
        gr + (size_t)(b * NN + i0 + ii) * HF + hh * FD + f4 * 4);
  }
  __syncthreads();

  const _Float16* glp = glh + (size_t)b * NN * HF + hh * FD;

  // ---- pre-pass: Al_s[j] (fp16 dot2, skew-stored), a_s[ii] ----
  {
    h2_t wv[16];
#pragma unroll
    for (int f2 = 0; f2 < 16; ++f2) { H2U v; v.u = w6h_s[f2]; wv[f2] = v.h; }
#pragma unroll
    for (int c = 0; c < 2; ++c) {
      const int j = t + 256 * c;
      const uint4* gp = (const uint4*)(glp + (size_t)j * HF);
      const uint4 g0 = gp[0], g1 = gp[1], g2 = gp[2], g3 = gp[3];
      float s0 = 0.f, s1 = 0.f;
      H2U v;
#define ALD(gu, i)                                                  \
  v.u = gu.x; s0 = __builtin_amdgcn_fdot2(v.h, wv[i+0], s0, false); \
  v.u = gu.y; s1 = __builtin_amdgcn_fdot2(v.h, wv[i+1], s1, false); \
  v.u = gu.z; s0 = __builtin_amdgcn_fdot2(v.h, wv[i+2], s0, false); \
  v.u = gu.w; s1 = __builtin_amdgcn_fdot2(v.h, wv[i+3], s1, false);
      ALD(g0, 0) ALD(g1, 4) ALD(g2, 8) ALD(g3, 12)
#undef ALD
      Al_s[ALIDX(j)] = s0 + s1;
    }
    if (t < IT) {
      float s = 0.f;
#pragma unroll
      for (int f = 0; f < FD; ++f) s = fmaf(q_s[t][f], w6_s[f], s);
      a_s[t] = s;
    }
  }
  __syncthreads();

  // ---- phase 1: scores -> packed fp16 ----
  {
    const int ii = t & 7;            // query row
    const int jl = t >> 3;           // 0..31, 16 j each
    const int j0 = jl * 16;
    h2_t qh[16], uh[16];
#pragma unroll
    for (int f2 = 0; f2 < 16; ++f2) {
      const float2 q2 = *(const float2*)&q_s[ii][2 * f2];
      qh[f2] = pkrtz(q2.x, q2.y);
      H2U v; v.u = uh_s[f2]; uh[f2] = v.h;
    }
    const float ar = a_s[ii];
    const int* adjp = adj + (size_t)(i0 + ii) * NN + j0;
    unsigned* erow = &e_s[ii][0];
#pragma unroll
    for (int jg = 0; jg < 4; ++jg) {
      const int jq = 4 * jg;
      const int4 a4 = *(const int4*)(adjp + jq);
      const int j = j0 + jq;
      float s0 = score32(glp + (size_t)(j + 0) * HF, qh, uh,
                         Al_s[ALIDX(j + 0)] + ar);
      float s1 = score32(glp + (size_t)(j + 1) * HF, qh, uh,
                         Al_s[ALIDX(j + 1)] + ar);
      float s2 = score32(glp + (size_t)(j + 2) * HF, qh, uh,
                         Al_s[ALIDX(j + 2)] + ar);
      float s3 = score32(glp + (size_t)(j + 3) * HF, qh, uh,
                         Al_s[ALIDX(j + 3)] + ar);
      s0 = a4.x ? s0 : MASKH;
      s1 = a4.y ? s1 : MASKH;
      s2 = a4.z ? s2 : MASKH;
      s3 = a4.w ? s3 : MASKH;
      H2U u0; u0.h = pkrtz(s0, s1);
      H2U u1; u1.h = pkrtz(s2, s3);
      erow[(j >> 1)] = u0.u;
      erow[(j >> 1) + 1] = u1.u;
    }
  }
  __syncthreads();

  // ---- phase 2: row softmax (8 rows x 32 lanes, shuffle width 32) ----
  {
    const int row = t >> 5;
    const int l32 = t & 31;
    unsigned* erow = &e_s[row][0];
    float m = MASKH;
#pragma unroll
    for (int c = 0; c < 8; ++c) {
      H2U v; v.u = erow[l32 + 32 * c];
      m = fmaxf(m, fmaxf((float)v.h.x, (float)v.h.y));
    }
#pragma unroll
    for (int off = 1; off < 32; off <<= 1) m = fmaxf(m, __shfl_xor(m, off));
    float s = 0.f;
#pragma unroll
    for (int c = 0; c < 8; ++c) {
      H2U v; v.u = erow[l32 + 32 * c];
      const float p0 = __expf((float)v.h.x - m);
      const float p1 = __expf((float)v.h.y - m);
      s += p0 + p1;
      H2U w; w.h = pkrtz(p0, p1);
      erow[l32 + 32 * c] = w.u;
    }
#pragma unroll
    for (int off = 1; off < 32; off <<= 1) s += __shfl_xor(s, off);
    if (l32 == 0) inv_l[row] = 1.f / s;
  }
  __syncthreads();

  // ---- phase 3: aggregation, j split in quarters ----
  {
    const int q = t >> 6;          // j-quarter
    const int ii = (t >> 3) & 7;   // query row
    const int f4 = t & 7;          // feature quad
    const unsigned* erow = &e_s[ii][0];
    const float* grp = gr + (size_t)b * NN * HF + hh * FD + f4 * 4;
    float4 acc = make_float4(0.f, 0.f, 0.f, 0.f);
#pragma unroll 8
    for (int jp = 64 * q; jp < 64 * q + 64; ++jp) {
      H2U v; v.u = erow[jp];
      const float p0 = (float)v.h.x, p1 = (float)v.h.y;
      const float4 v0 = *(const float4*)(grp + (size_t)(2 * jp) * HF);
      const float4 v1 = *(const float4*)(grp + (size_t)(2 * jp + 1) * HF);
      acc.x = fmaf(p0, v0.x, fmaf(p1, v1.x, acc.x));
      acc.y = fmaf(p0, v0.y, fmaf(p1, v1.y, acc.y));
      acc.z = fmaf(p0, v0.z, fmaf(p1, v1.z, acc.z));
      acc.w = fmaf(p0, v0.w, fmaf(p1, v1.w, acc.w));
    }
    __syncthreads();
    if (q) m_s[q - 1][ii][f4] = acc;
    __syncthreads();
    if (q == 0) {
      const float4 p1v = m_s[0][ii][f4];
      const float4 p2v = m_s[1][ii][f4];
      const float4 p3v = m_s[2][ii][f4];
      const float sc = inv_l[ii];
      float4 r;
      r.x = (acc.x + p1v.x + p2v.x + p3v.x) * sc;
      r.y = (acc.y + p1v.y + p2v.y + p3v.y) * sc;
      r.z = (acc.z + p1v.z + p2v.z + p3v.z) * sc;
      r.w = (acc.w + p1v.w + p2v.w + p3v.w) * sc;
      *(float4*)(out + (size_t)(b * NN + i0 + ii) * HF + hh * FD + f4 * 4) = r;
    }
  }
}

// ---------------------------------------------------------------------------
extern "C" void kernel_launch(void* const* d_in, const int* in_sizes, int n_in,
                              void* d_out, int out_size, void* d_ws,
                              size_t ws_size, hipStream_t stream) {
  const float* h = (const float*)d_in[0];
  const int* adj = (const int*)d_in[1];
  const float* Wl = (const float*)d_in[2];
  const float* Wr = (const float*)d_in[3];
  const float* aw = (const float*)d_in[4];
  float* out = (float*)d_out;

  _Float16* glh = (_Float16*)d_ws;                              // 1 MB fp16
  float* gr = (float*)((char*)d_ws + (size_t)BB * NN * HF * 2); // 2 MB fp32

  dim3 gg(BB * NN / 8, 2, 1);
  gemm_dual<<<gg, 256, 0, stream>>>(h, Wl, Wr, glh, gr);

  dim3 ga(NH, NN / IT, BB);
  gat_attn<<<ga, 256, 0, stream>>>(glh, gr, adj, aw, out);
}

// Round 7
// 139.515 us; speedup vs baseline: 1.0028x; 1.0028x over previous
//
#include <hip/hip_runtime.h>
#include <math.h>

#define BB 4
#define NN 512
#define FIN 256
#define NH 8
#define FD 32
#define HF 256               // NH * FD
#define MASKH (-60000.0f)    // fp16-exact mask; same softmax semantics as -1e6
// leaky(x) = max(x, 0.21x) = CA*x + CB*|x|
#define CA 0.605f
#define CB 0.395f
#define IT 16                // i-tile rows (R5 config; R6's IT=8 regressed)
#define ESTR 265             // uints per e_s row (odd -> 2-way banks, free)
#define ALIDX(j) ((j) + ((j) >> 4))  // skew for stride-16/32 reads

typedef _Float16 h2_t __attribute__((ext_vector_type(2)));
union H2U { unsigned u; h2_t h; };

__device__ __forceinline__ h2_t pkrtz(float a, float b) {
  auto r = __builtin_amdgcn_cvt_pkrtz(a, b);
  union { decltype(r) f; h2_t h; } u;
  u.f = r;
  return u.h;
}

// x = g2 + q2 (v_pk_add_f16); |x| (v_and 0x7fff7fff); acc += u2.|x| (v_dot2)
__device__ __forceinline__ float acc2(unsigned g, h2_t q, h2_t u, float acc) {
  H2U v; v.u = g;
  h2_t s = v.h + q;
  H2U a; a.h = s; a.u &= 0x7fff7fffu;
  return __builtin_amdgcn_fdot2(a.h, u, acc, false);
}

// 32-feature score for one j from 4 preloaded uint4
__device__ __forceinline__ float score16(uint4 g0, uint4 g1, uint4 g2, uint4 g3,
                                         const h2_t* qh, const h2_t* uh,
                                         float init) {
  float e0 = init, e1 = 0.f;
  e0 = acc2(g0.x, qh[0], uh[0], e0);
  e1 = acc2(g0.y, qh[1], uh[1], e1);
  e0 = acc2(g0.z, qh[2], uh[2], e0);
  e1 = acc2(g0.w, qh[3], uh[3], e1);
  e0 = acc2(g1.x, qh[4], uh[4], e0);
  e1 = acc2(g1.y, qh[5], uh[5], e1);
  e0 = acc2(g1.z, qh[6], uh[6], e0);
  e1 = acc2(g1.w, qh[7], uh[7], e1);
  e0 = acc2(g2.x, qh[8], uh[8], e0);
  e1 = acc2(g2.y, qh[9], uh[9], e1);
  e0 = acc2(g2.z, qh[10], uh[10], e0);
  e1 = acc2(g2.w, qh[11], uh[11], e1);
  e0 = acc2(g3.x, qh[12], uh[12], e0);
  e1 = acc2(g3.y, qh[13], uh[13], e1);
  e0 = acc2(g3.z, qh[14], uh[14], e0);
  e1 = acc2(g3.w, qh[15], uh[15], e1);
  return e0 + e1;
}

// ---------------------------------------------------------------------------
// Kernel 1: dual GEMM g = h @ W. y==0 -> gl fp16, y==1 -> gr fp32.
// ---------------------------------------------------------------------------
__global__ __launch_bounds__(256) void gemm_dual(
    const float* __restrict__ h, const float* __restrict__ Wl,
    const float* __restrict__ Wr, _Float16* __restrict__ glh,
    float* __restrict__ gr) {
  const int t = threadIdx.x;
  const int row0 = blockIdx.x * 8;
  const float* __restrict__ W = blockIdx.y ? Wr : Wl;

  float acc[8] = {0.f, 0.f, 0.f, 0.f, 0.f, 0.f, 0.f, 0.f};
  const float* Wp = W + t;
  const float* hp = h + (size_t)row0 * FIN;

#pragma unroll 2
  for (int k4 = 0; k4 < FIN / 4; ++k4) {
    float4 hv[8];
#pragma unroll
    for (int r = 0; r < 8; ++r)
      hv[r] = *(const float4*)(hp + r * FIN + 4 * k4);
#pragma unroll
    for (int kk = 0; kk < 4; ++kk) {
      const float w = Wp[(size_t)(4 * k4 + kk) * HF];
#pragma unroll
      for (int r = 0; r < 8; ++r) {
        const float hval = (kk == 0) ? hv[r].x
                         : (kk == 1) ? hv[r].y
                         : (kk == 2) ? hv[r].z : hv[r].w;
        acc[r] = fmaf(hval, w, acc[r]);
      }
    }
  }

  if (blockIdx.y == 0) {
    _Float16* gp = glh + (size_t)row0 * HF + t;
#pragma unroll
    for (int r = 0; r < 8; ++r) gp[(size_t)r * HF] = (_Float16)acc[r];
  } else {
    float* gp = gr + (size_t)row0 * HF + t;
#pragma unroll
    for (int r = 0; r < 8; ++r) gp[(size_t)r * HF] = acc[r];
  }
}

// ---------------------------------------------------------------------------
// Kernel 2: fused GATv2 attention. Block = (head hh, 16-row i-tile, batch b).
// R7: explicit double-buffered register pipelines in phases 1 & 3 to keep
// 8-16 L2 loads in flight per thread (R6 ran at VGPR=60 -> ~1 j in flight ->
// 65% stall). Buffers are named locals (constant-indexed) -> registers.
// ---------------------------------------------------------------------------
__global__ __launch_bounds__(256) void gat_attn(
    const _Float16* __restrict__ glh, const float* __restrict__ gr,
    const int* __restrict__ adj, const float* __restrict__ aw,
    float* __restrict__ out) {
  __shared__ unsigned e_s[IT][ESTR];  // packed fp16 scores -> p; 17 KB
  __shared__ float Al_s[544];         // skew-indexed CA*(w.gl[j,:])
  __shared__ float q_s[IT][36];       // gr rows (fp32) of this i-tile
  __shared__ float w6_s[FD];          // CA * w
  __shared__ unsigned uh_s[16];       // CB * w packed fp16
  __shared__ unsigned w6h_s[16];      // CA * w packed fp16
  __shared__ float a_s[IT];           // CA * (w . gr[i,:])
  __shared__ float inv_l[IT];
  __shared__ float4 m_s[IT][8];       // phase-3 half partials

  const int t = threadIdx.x;
  const int hh = blockIdx.x;
  const int i0 = blockIdx.y * IT;
  const int b = blockIdx.z;

  if (t < FD) w6_s[t] = CA * aw[t];
  if (t < 16) {
    const float w0 = aw[2 * t], w1 = aw[2 * t + 1];
    H2U p0; p0.h = pkrtz(CB * w0, CB * w1);
    uh_s[t] = p0.u;
    H2U p1; p1.h = pkrtz(CA * w0, CA * w1);
    w6h_s[t] = p1.u;
  }
  if (t < 8 * IT) {  // stage q: IT x 32 floats
    const int ii = t >> 3, f4 = t & 7;
    *(float4*)&q_s[ii][f4 * 4] = *(const float4*)(
        gr + (size_t)(b * NN + i0 + ii) * HF + hh * FD + f4 * 4);
  }
  __syncthreads();

  const _Float16* glp = glh + (size_t)b * NN * HF + hh * FD;

  // ---- pre-pass: Al_s[j] (skew-stored), a_s[ii] ----
  {
    h2_t wv[16];
#pragma unroll
    for (int f2 = 0; f2 < 16; ++f2) { H2U v; v.u = w6h_s[f2]; wv[f2] = v.h; }
#pragma unroll
    for (int c = 0; c < 2; ++c) {
      const int j = t + 256 * c;
      const uint4* gp = (const uint4*)(glp + (size_t)j * HF);
      const uint4 g0 = gp[0], g1 = gp[1], g2 = gp[2], g3 = gp[3];
      float s0 = 0.f, s1 = 0.f;
      H2U v;
#define ALD(gu, i)                                                  \
  v.u = gu.x; s0 = __builtin_amdgcn_fdot2(v.h, wv[i+0], s0, false); \
  v.u = gu.y; s1 = __builtin_amdgcn_fdot2(v.h, wv[i+1], s1, false); \
  v.u = gu.z; s0 = __builtin_amdgcn_fdot2(v.h, wv[i+2], s0, false); \
  v.u = gu.w; s1 = __builtin_amdgcn_fdot2(v.h, wv[i+3], s1, false);
      ALD(g0, 0) ALD(g1, 4) ALD(g2, 8) ALD(g3, 12)
#undef ALD
      Al_s[ALIDX(j)] = s0 + s1;
    }
    if (t < IT) {
      float s = 0.f;
#pragma unroll
      for (int f = 0; f < FD; ++f) s = fmaf(q_s[t][f], w6_s[f], s);
      a_s[t] = s;
    }
  }
  __syncthreads();

  // ---- phase 1: scores, software-pipelined (2-row stages, A/B banks) ----
  {
    const int ii = t & 15;   // query row
    const int jl = t >> 4;   // 0..15, 32 consecutive j each
    const int j0 = jl * 32;
    h2_t qh[16], uh[16];
#pragma unroll
    for (int f2 = 0; f2 < 16; ++f2) {
      const float2 q2 = *(const float2*)&q_s[ii][2 * f2];
      qh[f2] = pkrtz(q2.x, q2.y);
      H2U v; v.u = uh_s[f2]; uh[f2] = v.h;
    }
    const float ar = a_s[ii];
    const int* adjp = adj + (size_t)(i0 + ii) * NN + j0;
    // all adjacency for this thread's 32 j, preloaded (8 int4 in flight)
    const int4 m0 = ((const int4*)adjp)[0];
    const int4 m1 = ((const int4*)adjp)[1];
    const int4 m2 = ((const int4*)adjp)[2];
    const int4 m3 = ((const int4*)adjp)[3];
    const int4 m4 = ((const int4*)adjp)[4];
    const int4 m5 = ((const int4*)adjp)[5];
    const int4 m6 = ((const int4*)adjp)[6];
    const int4 m7 = ((const int4*)adjp)[7];
    unsigned* erow = &e_s[ii][j0 >> 1];

    uint4 A0, A1, A2, A3, A4, A5, A6, A7;
    uint4 B0, B1, B2, B3, B4, B5, B6, B7;

#define LDA(jj) {                                                   \
    const uint4* _p = (const uint4*)(glp + (size_t)(jj) * HF);      \
    const uint4* _q = (const uint4*)(glp + (size_t)((jj) + 1) * HF);\
    A0 = _p[0]; A1 = _p[1]; A2 = _p[2]; A3 = _p[3];                 \
    A4 = _q[0]; A5 = _q[1]; A6 = _q[2]; A7 = _q[3]; }
#define LDB(jj) {                                                   \
    const uint4* _p = (const uint4*)(glp + (size_t)(jj) * HF);      \
    const uint4* _q = (const uint4*)(glp + (size_t)((jj) + 1) * HF);\
    B0 = _p[0]; B1 = _p[1]; B2 = _p[2]; B3 = _p[3];                 \
    B4 = _q[0]; B5 = _q[1]; B6 = _q[2]; B7 = _q[3]; }
#define CMA(s, mx, my) {                                                     \
    float _e0 = score16(A0, A1, A2, A3, qh, uh, Al_s[ALIDX(j0+2*(s))] + ar); \
    float _e1 = score16(A4, A5, A6, A7, qh, uh, Al_s[ALIDX(j0+2*(s)+1)] + ar);\
    _e0 = (mx) ? _e0 : MASKH; _e1 = (my) ? _e1 : MASKH;                      \
    H2U _u; _u.h = pkrtz(_e0, _e1); erow[s] = _u.u; }
#define CMB(s, mx, my) {                                                     \
    float _e0 = score16(B0, B1, B2, B3, qh, uh, Al_s[ALIDX(j0+2*(s))] + ar); \
    float _e1 = score16(B4, B5, B6, B7, qh, uh, Al_s[ALIDX(j0+2*(s)+1)] + ar);\
    _e0 = (mx) ? _e0 : MASKH; _e1 = (my) ? _e1 : MASKH;                      \
    H2U _u; _u.h = pkrtz(_e0, _e1); erow[s] = _u.u; }

    LDA(j0);
    LDB(j0 + 2);
    CMA(0, m0.x, m0.y);   LDA(j0 + 4);
    CMB(1, m0.z, m0.w);   LDB(j0 + 6);
    CMA(2, m1.x, m1.y);   LDA(j0 + 8);
    CMB(3, m1.z, m1.w);   LDB(j0 + 10);
    CMA(4, m2.x, m2.y);   LDA(j0 + 12);
    CMB(5, m2.z, m2.w);   LDB(j0 + 14);
    CMA(6, m3.x, m3.y);   LDA(j0 + 16);
    CMB(7, m3.z, m3.w);   LDB(j0 + 18);
    CMA(8, m4.x, m4.y);   LDA(j0 + 20);
    CMB(9, m4.z, m4.w);   LDB(j0 + 22);
    CMA(10, m5.x, m5.y);  LDA(j0 + 24);
    CMB(11, m5.z, m5.w);  LDB(j0 + 26);
    CMA(12, m6.x, m6.y);  LDA(j0 + 28);
    CMB(13, m6.z, m6.w);  LDB(j0 + 30);
    CMA(14, m7.x, m7.y);
    CMB(15, m7.z, m7.w);
#undef LDA
#undef LDB
#undef CMA
#undef CMB
  }
  __syncthreads();

  // ---- phase 2: row softmax (16 rows x 16 lanes) ----
  {
    const int lane = t & 63;
    const int row = ((t >> 6) << 2) + (lane >> 4);
    const int l16 = lane & 15;
    unsigned* erow = &e_s[row][0];
    float m = MASKH;
#pragma unroll
    for (int c = 0; c < 16; ++c) {
      H2U v; v.u = erow[l16 + 16 * c];
      m = fmaxf(m, fmaxf((float)v.h.x, (float)v.h.y));
    }
#pragma unroll
    for (int off = 1; off < 16; off <<= 1) m = fmaxf(m, __shfl_xor(m, off));
    float s = 0.f;
#pragma unroll
    for (int c = 0; c < 16; ++c) {
      H2U v; v.u = erow[l16 + 16 * c];
      const float p0 = __expf((float)v.h.x - m);
      const float p1 = __expf((float)v.h.y - m);
      s += p0 + p1;
      H2U w; w.h = pkrtz(p0, p1);
      erow[l16 + 16 * c] = w.u;
    }
#pragma unroll
    for (int off = 1; off < 16; off <<= 1) s += __shfl_xor(s, off);
    if (l16 == 0) inv_l[row] = 1.f / s;
  }
  __syncthreads();

  // ---- phase 3: aggregation, software-pipelined (4-pair stages, A/B) ----
  {
    const int half = t >> 7;       // j-half
    const int ii = (t >> 3) & 15;  // query row
    const int f4 = t & 7;          // feature quad
    const unsigned* erow = &e_s[ii][half * 128];
    const float* grp = gr + (size_t)b * NN * HF + (size_t)half * 256 * HF +
                       hh * FD + f4 * 4;
    float4 acc = make_float4(0.f, 0.f, 0.f, 0.f);

    float4 A0, A1, A2, A3, A4, A5, A6, A7;
    float4 B0, B1, B2, B3, B4, B5, B6, B7;
    unsigned pa0, pa1, pa2, pa3, pb0, pb1, pb2, pb3;

#define GLD(r) (*(const float4*)(grp + (size_t)(r) * HF))
#define P3LA(jp) {                                                  \
    A0 = GLD(2*(jp));   A1 = GLD(2*(jp)+1); A2 = GLD(2*(jp)+2);     \
    A3 = GLD(2*(jp)+3); A4 = GLD(2*(jp)+4); A5 = GLD(2*(jp)+5);     \
    A6 = GLD(2*(jp)+6); A7 = GLD(2*(jp)+7);                         \
    pa0 = erow[jp]; pa1 = erow[(jp)+1];                             \
    pa2 = erow[(jp)+2]; pa3 = erow[(jp)+3]; }
#define P3LB(jp) {                                                  \
    B0 = GLD(2*(jp));   B1 = GLD(2*(jp)+1); B2 = GLD(2*(jp)+2);     \
    B3 = GLD(2*(jp)+3); B4 = GLD(2*(jp)+4); B5 = GLD(2*(jp)+5);     \
    B6 = GLD(2*(jp)+6); B7 = GLD(2*(jp)+7);                         \
    pb0 = erow[jp]; pb1 = erow[(jp)+1];                             \
    pb2 = erow[(jp)+2]; pb3 = erow[(jp)+3]; }
#define FMA2(P, Q, p0, p1)                                          \
    acc.x = fmaf(p0, P.x, fmaf(p1, Q.x, acc.x));                    \
    acc.y = fmaf(p0, P.y, fmaf(p1, Q.y, acc.y));                    \
    acc.z = fmaf(p0, P.z, fmaf(p1, Q.z, acc.z));                    \
    acc.w = fmaf(p0, P.w, fmaf(p1, Q.w, acc.w));
#define P3CA() {                                                    \
    H2U _v; float _p0, _p1;                                         \
    _v.u = pa0; _p0 = (float)_v.h.x; _p1 = (float)_v.h.y;           \
    FMA2(A0, A1, _p0, _p1)                                          \
    _v.u = pa1; _p0 = (float)_v.h.x; _p1 = (float)_v.h.y;           \
    FMA2(A2, A3, _p0, _p1)                                          \
    _v.u = pa2; _p0 = (float)_v.h.x; _p1 = (float)_v.h.y;           \
    FMA2(A4, A5, _p0, _p1)                                          \
    _v.u = pa3; _p0 = (float)_v.h.x; _p1 = (float)_v.h.y;           \
    FMA2(A6, A7, _p0, _p1) }
#define P3CB() {                                                    \
    H2U _v; float _p0, _p1;                                         \
    _v.u = pb0; _p0 = (float)_v.h.x; _p1 = (float)_v.h.y;           \
    FMA2(B0, B1, _p0, _p1)                                          \
    _v.u = pb1; _p0 = (float)_v.h.x; _p1 = (float)_v.h.y;           \
    FMA2(B2, B3, _p0, _p1)                                          \
    _v.u = pb2; _p0 = (float)_v.h.x; _p1 = (float)_v.h.y;           \
    FMA2(B4, B5, _p0, _p1)                                          \
    _v.u = pb3; _p0 = (float)_v.h.x; _p1 = (float)_v.h.y;           \
    FMA2(B6, B7, _p0, _p1) }

    P3LA(0);
    P3LB(4);
#pragma unroll 2
    for (int g = 0; g < 16; ++g) {
      const int jp = 8 * g;
      P3CA();
      if (g < 15) P3LA(jp + 8);
      P3CB();
      if (g < 15) P3LB(jp + 12);
    }
#undef GLD
#undef P3LA
#undef P3LB
#undef FMA2
#undef P3CA
#undef P3CB

    __syncthreads();
    if (half) m_s[ii][f4] = acc;
    __syncthreads();
    if (!half) {
      const float4 o = m_s[ii][f4];
      const float sc = inv_l[ii];
      float4 r;
      r.x = (acc.x + o.x) * sc;
      r.y = (acc.y + o.y) * sc;
      r.z = (acc.z + o.z) * sc;
      r.w = (acc.w + o.w) * sc;
      *(float4*)(out + (size_t)(b * NN + i0 + ii) * HF + hh * FD + f4 * 4) = r;
    }
  }
}

// ---------------------------------------------------------------------------
extern "C" void kernel_launch(void* const* d_in, const int* in_sizes, int n_in,
                              void* d_out, int out_size, void* d_ws,
                              size_t ws_size, hipStream_t stream) {
  const float* h = (const float*)d_in[0];
  const int* adj = (const int*)d_in[1];
  const float* Wl = (const float*)d_in[2];
  const float* Wr = (const float*)d_in[3];
  const float* aw = (const float*)d_in[4];
  float* out = (float*)d_out;

  _Float16* glh = (_Float16*)d_ws;                              // 1 MB fp16
  float* gr = (float*)((char*)d_ws + (size_t)BB * NN * HF * 2); // 2 MB fp32

  dim3 gg(BB * NN / 8, 2, 1);
  gemm_dual<<<gg, 256, 0, stream>>>(h, Wl, Wr, glh, gr);

  dim3 ga(NH, NN / IT, BB);
  gat_attn<<<ga, 256, 0, stream>>>(glh, gr, adj, aw, out);
}

// Round 8
// 127.578 us; speedup vs baseline: 1.0966x; 1.0936x over previous
//
#include <hip/hip_runtime.h>
#include <math.h>

#define BB 4
#define NN 512
#define FIN 256
#define NH 8
#define FD 32
#define HF 256               // NH * FD
#define MASKH (-60000.0f)    // fp16-exact mask; same softmax semantics as -1e6
// leaky(x) = max(x, 0.21x) = CA*x + CB*|x|
#define CA 0.605f
#define CB 0.395f
#define IT 32                // i-tile rows; grid = 512 blocks = exactly 2/CU
#define ESTR 265             // uints per e_s row (odd -> spread banks)

typedef _Float16 h2_t __attribute__((ext_vector_type(2)));
union H2U { unsigned u; h2_t h; };

__device__ __forceinline__ h2_t pkrtz(float a, float b) {
  auto r = __builtin_amdgcn_cvt_pkrtz(a, b);
  union { decltype(r) f; h2_t h; } u;
  u.f = r;
  return u.h;
}

// x = g2 + q2 (v_pk_add_f16); |x| (v_and 0x7fff7fff); acc += u2.|x| (v_dot2)
__device__ __forceinline__ float acc2(unsigned g, h2_t q, h2_t u, float acc) {
  H2U v; v.u = g;
  h2_t s = v.h + q;
  H2U a; a.h = s; a.u &= 0x7fff7fffu;
  return __builtin_amdgcn_fdot2(a.h, u, acc, false);
}

// 32-feature score for one j from 4 uint4 (8 fp16 each)
__device__ __forceinline__ float score16(uint4 g0, uint4 g1, uint4 g2, uint4 g3,
                                         const h2_t* qh, const h2_t* uh,
                                         float init) {
  float e0 = init, e1 = 0.f;
  e0 = acc2(g0.x, qh[0], uh[0], e0);
  e1 = acc2(g0.y, qh[1], uh[1], e1);
  e0 = acc2(g0.z, qh[2], uh[2], e0);
  e1 = acc2(g0.w, qh[3], uh[3], e1);
  e0 = acc2(g1.x, qh[4], uh[4], e0);
  e1 = acc2(g1.y, qh[5], uh[5], e1);
  e0 = acc2(g1.z, qh[6], uh[6], e0);
  e1 = acc2(g1.w, qh[7], uh[7], e1);
  e0 = acc2(g2.x, qh[8], uh[8], e0);
  e1 = acc2(g2.y, qh[9], uh[9], e1);
  e0 = acc2(g2.z, qh[10], uh[10], e0);
  e1 = acc2(g2.w, qh[11], uh[11], e1);
  e0 = acc2(g3.x, qh[12], uh[12], e0);
  e1 = acc2(g3.y, qh[13], uh[13], e1);
  e0 = acc2(g3.z, qh[14], uh[14], e0);
  e1 = acc2(g3.w, qh[15], uh[15], e1);
  return e0 + e1;
}

// ---------------------------------------------------------------------------
// Kernel 1: dual GEMM g = h @ W. y==0 -> gl fp16, y==1 -> gr fp32. (unchanged)
// ---------------------------------------------------------------------------
__global__ __launch_bounds__(256) void gemm_dual(
    const float* __restrict__ h, const float* __restrict__ Wl,
    const float* __restrict__ Wr, _Float16* __restrict__ glh,
    float* __restrict__ gr) {
  const int t = threadIdx.x;
  const int row0 = blockIdx.x * 8;
  const float* __restrict__ W = blockIdx.y ? Wr : Wl;

  float acc[8] = {0.f, 0.f, 0.f, 0.f, 0.f, 0.f, 0.f, 0.f};
  const float* Wp = W + t;
  const float* hp = h + (size_t)row0 * FIN;

#pragma unroll 2
  for (int k4 = 0; k4 < FIN / 4; ++k4) {
    float4 hv[8];
#pragma unroll
    for (int r = 0; r < 8; ++r)
      hv[r] = *(const float4*)(hp + r * FIN + 4 * k4);
#pragma unroll
    for (int kk = 0; kk < 4; ++kk) {
      const float w = Wp[(size_t)(4 * k4 + kk) * HF];
#pragma unroll
      for (int r = 0; r < 8; ++r) {
        const float hval = (kk == 0) ? hv[r].x
                         : (kk == 1) ? hv[r].y
                         : (kk == 2) ? hv[r].z : hv[r].w;
        acc[r] = fmaf(hval, w, acc[r]);
      }
    }
  }

  if (blockIdx.y == 0) {
    _Float16* gp = glh + (size_t)row0 * HF + t;
#pragma unroll
    for (int r = 0; r < 8; ++r) gp[(size_t)r * HF] = (_Float16)acc[r];
  } else {
    float* gp = gr + (size_t)row0 * HF + t;
#pragma unroll
    for (int r = 0; r < 8; ++r) gp[(size_t)r * HF] = acc[r];
  }
}

// ---------------------------------------------------------------------------
// Kernel 2: fused GATv2 attention. Block = (head hh, 32-row i-tile, batch b).
// R8: gl slice (32 KB fp16) staged to LDS in the pre-pass (which reads it
// anyway for Al) -> phase 1 reads ds_read_b128 instead of ~200-cyc L2 loads.
// IT=32: grid 512 = exactly 2 blocks/CU (LDS 67 KB), single round, no tail;
// phase 3 owns full rows (no partial merge). (256,2) frees VGPR cap to 256;
// no indexed reg arrays (R2 spill lesson), no hand pipelining (R7 lesson).
// ---------------------------------------------------------------------------
__global__ __launch_bounds__(256, 2) void gat_attn(
    const _Float16* __restrict__ glh, const float* __restrict__ gr,
    const int* __restrict__ adj, const float* __restrict__ aw,
    float* __restrict__ out) {
  __shared__ uint4 gl4[4][NN];        // 32 KB: gl slice fp16, k-major
  __shared__ unsigned e_s[IT][ESTR];  // 33.9 KB: packed fp16 scores -> p
  __shared__ float Al_s[NN];          // 2 KB: CA*(w.gl[j,:])
  __shared__ float inv_l[IT];

  const int t = threadIdx.x;
  const int hh = blockIdx.x;
  const int i0 = blockIdx.y * IT;
  const int b = blockIdx.z;
  const int ii = t & 31;   // phase-1 query row
  const int jg = t >> 5;   // 0..7, 64 j each

  const _Float16* glp = glh + (size_t)b * NN * HF + hh * FD;

  // ---- per-thread prep: aw -> wv/uh fp16 pairs; q row -> qh + a_r ----
  h2_t wv[16], uh[16], qh[16];
  float a_r = 0.f;
  {
    const float* qp = gr + (size_t)(b * NN + i0 + ii) * HF + hh * FD;
#pragma unroll
    for (int f4 = 0; f4 < 8; ++f4) {
      const float4 w4 = *(const float4*)(aw + 4 * f4);
      const float4 q4 = *(const float4*)(qp + 4 * f4);
      wv[2 * f4] = pkrtz(CA * w4.x, CA * w4.y);
      wv[2 * f4 + 1] = pkrtz(CA * w4.z, CA * w4.w);
      uh[2 * f4] = pkrtz(CB * w4.x, CB * w4.y);
      uh[2 * f4 + 1] = pkrtz(CB * w4.z, CB * w4.w);
      qh[2 * f4] = pkrtz(q4.x, q4.y);
      qh[2 * f4 + 1] = pkrtz(q4.z, q4.w);
      a_r = fmaf(CA * w4.x, q4.x, a_r);
      a_r = fmaf(CA * w4.y, q4.y, a_r);
      a_r = fmaf(CA * w4.z, q4.z, a_r);
      a_r = fmaf(CA * w4.w, q4.w, a_r);
    }
  }

  // ---- stage gl slice -> LDS (k-major, lane-contiguous writes) + Al ----
#pragma unroll
  for (int c = 0; c < 2; ++c) {
    const int j = t + 256 * c;
    const uint4* gp = (const uint4*)(glp + (size_t)j * HF);
    const uint4 g0 = gp[0], g1 = gp[1], g2 = gp[2], g3 = gp[3];
    gl4[0][j] = g0;
    gl4[1][j] = g1;
    gl4[2][j] = g2;
    gl4[3][j] = g3;
    float s0 = 0.f, s1 = 0.f;
    H2U v;
#define ALD(gu, i)                                                  \
  v.u = gu.x; s0 = __builtin_amdgcn_fdot2(v.h, wv[i+0], s0, false); \
  v.u = gu.y; s1 = __builtin_amdgcn_fdot2(v.h, wv[i+1], s1, false); \
  v.u = gu.z; s0 = __builtin_amdgcn_fdot2(v.h, wv[i+2], s0, false); \
  v.u = gu.w; s1 = __builtin_amdgcn_fdot2(v.h, wv[i+3], s1, false);
    ALD(g0, 0) ALD(g1, 4) ALD(g2, 8) ALD(g3, 12)
#undef ALD
    Al_s[j] = s0 + s1;
  }
  __syncthreads();

  // ---- phase 1: scores from LDS gl (broadcast b128 reads) ----
  {
    unsigned* erow = &e_s[ii][jg * 32];
    const int* adjp = adj + (size_t)(i0 + ii) * NN + jg * 64;
#pragma unroll 4
    for (int g4 = 0; g4 < 16; ++g4) {
      const int4 a4 = ((const int4*)adjp)[g4];
      const int j = jg * 64 + 4 * g4;
      float e0 = score16(gl4[0][j], gl4[1][j], gl4[2][j], gl4[3][j], qh, uh,
                         Al_s[j] + a_r);
      float e1 = score16(gl4[0][j + 1], gl4[1][j + 1], gl4[2][j + 1],
                         gl4[3][j + 1], qh, uh, Al_s[j + 1] + a_r);
      float e2 = score16(gl4[0][j + 2], gl4[1][j + 2], gl4[2][j + 2],
                         gl4[3][j + 2], qh, uh, Al_s[j + 2] + a_r);
      float e3 = score16(gl4[0][j + 3], gl4[1][j + 3], gl4[2][j + 3],
                         gl4[3][j + 3], qh, uh, Al_s[j + 3] + a_r);
      e0 = a4.x ? e0 : MASKH;
      e1 = a4.y ? e1 : MASKH;
      e2 = a4.z ? e2 : MASKH;
      e3 = a4.w ? e3 : MASKH;
      H2U u0; u0.h = pkrtz(e0, e1);
      H2U u1; u1.h = pkrtz(e2, e3);
      erow[2 * g4] = u0.u;
      erow[2 * g4 + 1] = u1.u;
    }
  }
  __syncthreads();

  // ---- phase 2: row softmax (32 rows x 8 lanes) ----
  {
    const int row = t >> 3;
    const int l8 = t & 7;
    unsigned* erow = &e_s[row][0];
    float m = MASKH;
#pragma unroll
    for (int c = 0; c < 32; ++c) {
      H2U v; v.u = erow[l8 + 8 * c];
      m = fmaxf(m, fmaxf((float)v.h.x, (float)v.h.y));
    }
#pragma unroll
    for (int off = 1; off < 8; off <<= 1) m = fmaxf(m, __shfl_xor(m, off));
    float s = 0.f;
#pragma unroll
    for (int c = 0; c < 32; ++c) {
      H2U v; v.u = erow[l8 + 8 * c];
      const float p0 = __expf((float)v.h.x - m);
      const float p1 = __expf((float)v.h.y - m);
      s += p0 + p1;
      H2U w; w.h = pkrtz(p0, p1);
      erow[l8 + 8 * c] = w.u;
    }
#pragma unroll
    for (int off = 1; off < 8; off <<= 1) s += __shfl_xor(s, off);
    if (l8 == 0) inv_l[row] = 1.f / s;
  }
  __syncthreads();

  // ---- phase 3: aggregation; each thread owns (row, f-quad) for all j ----
  {
    const int pii = t >> 3;  // 0..31
    const int f4 = t & 7;
    const unsigned* erow = &e_s[pii][0];
    const float* grp = gr + (size_t)b * NN * HF + hh * FD + f4 * 4;
    float4 acc = make_float4(0.f, 0.f, 0.f, 0.f);
#pragma unroll 8
    for (int jp = 0; jp < 256; ++jp) {
      H2U v; v.u = erow[jp];
      const float p0 = (float)v.h.x, p1 = (float)v.h.y;
      const float4 v0 = *(const float4*)(grp + (size_t)(2 * jp) * HF);
      const float4 v1 = *(const float4*)(grp + (size_t)(2 * jp + 1) * HF);
      acc.x = fmaf(p0, v0.x, fmaf(p1, v1.x, acc.x));
      acc.y = fmaf(p0, v0.y, fmaf(p1, v1.y, acc.y));
      acc.z = fmaf(p0, v0.z, fmaf(p1, v1.z, acc.z));
      acc.w = fmaf(p0, v0.w, fmaf(p1, v1.w, acc.w));
    }
    const float sc = inv_l[pii];
    float4 r;
    r.x = acc.x * sc;
    r.y = acc.y * sc;
    r.z = acc.z * sc;
    r.w = acc.w * sc;
    *(float4*)(out + (size_t)(b * NN + i0 + pii) * HF + hh * FD + f4 * 4) = r;
  }
}

// ---------------------------------------------------------------------------
extern "C" void kernel_launch(void* const* d_in, const int* in_sizes, int n_in,
                              void* d_out, int out_size, void* d_ws,
                              size_t ws_size, hipStream_t stream) {
  const float* h = (const float*)d_in[0];
  const int* adj = (const int*)d_in[1];
  const float* Wl = (const float*)d_in[2];
  const float* Wr = (const float*)d_in[3];
  const float* aw = (const float*)d_in[4];
  float* out = (float*)d_out;

  _Float16* glh = (_Float16*)d_ws;                              // 1 MB fp16
  float* gr = (float*)((char*)d_ws + (size_t)BB * NN * HF * 2); // 2 MB fp32

  dim3 gg(BB * NN / 8, 2, 1);
  gemm_dual<<<gg, 256, 0, stream>>>(h, Wl, Wr, glh, gr);

  dim3 ga(NH, NN / IT, BB);
  gat_attn<<<ga, 256, 0, stream>>>(glh, gr, adj, aw, out);
}

// Round 9
// 105.138 us; speedup vs baseline: 1.3307x; 1.2134x over previous
//
#include <hip/hip_runtime.h>
#include <math.h>

#define BB 4
#define NN 512
#define FIN 256
#define NH 8
#define FD 32
#define HF 256               // NH * FD
#define MASKH (-60000.0f)    // fp16-exact mask; same softmax semantics as -1e6
// leaky(x) = max(x, 0.21x) = CA*x + CB*|x|
#define CA 0.605f
#define CB 0.395f
#define IT 32                // i-tile rows; grid = 512 blocks = exactly 2/CU
#define ESTR 268             // uints/e_s row: 1072B = 16B-aligned, bank 12r+c
#define GTS 260              // grT row stride in uints (520 fp16, 16B-aligned)

typedef _Float16 h2_t __attribute__((ext_vector_type(2)));
union H2U { unsigned u; h2_t h; };
typedef __fp16 v8h __attribute__((ext_vector_type(8)));  // MFMA a/b frag
typedef float v4f __attribute__((ext_vector_type(4)));   // MFMA acc
union U8 { uint4 u4; v8h h; };

__device__ __forceinline__ h2_t pkrtz(float a, float b) {
  auto r = __builtin_amdgcn_cvt_pkrtz(a, b);
  union { decltype(r) f; h2_t h; } u;
  u.f = r;
  return u.h;
}
__device__ __forceinline__ unsigned pkrtz_u(float a, float b) {
  H2U u; u.h = pkrtz(a, b);
  return u.u;
}

// x = g2 + q2 (v_pk_add_f16); |x| (v_and 0x7fff7fff); acc += u2.|x| (v_dot2)
__device__ __forceinline__ float acc2(unsigned g, h2_t q, h2_t u, float acc) {
  H2U v; v.u = g;
  h2_t s = v.h + q;
  H2U a; a.h = s; a.u &= 0x7fff7fffu;
  return __builtin_amdgcn_fdot2(a.h, u, acc, false);
}

// 32-feature score for one j from 4 uint4 (8 fp16 each)
__device__ __forceinline__ float score16(uint4 g0, uint4 g1, uint4 g2, uint4 g3,
                                         const h2_t* qh, const h2_t* uh,
                                         float init) {
  float e0 = init, e1 = 0.f;
  e0 = acc2(g0.x, qh[0], uh[0], e0);
  e1 = acc2(g0.y, qh[1], uh[1], e1);
  e0 = acc2(g0.z, qh[2], uh[2], e0);
  e1 = acc2(g0.w, qh[3], uh[3], e1);
  e0 = acc2(g1.x, qh[4], uh[4], e0);
  e1 = acc2(g1.y, qh[5], uh[5], e1);
  e0 = acc2(g1.z, qh[6], uh[6], e0);
  e1 = acc2(g1.w, qh[7], uh[7], e1);
  e0 = acc2(g2.x, qh[8], uh[8], e0);
  e1 = acc2(g2.y, qh[9], uh[9], e1);
  e0 = acc2(g2.z, qh[10], uh[10], e0);
  e1 = acc2(g2.w, qh[11], uh[11], e1);
  e0 = acc2(g3.x, qh[12], uh[12], e0);
  e1 = acc2(g3.y, qh[13], uh[13], e1);
  e0 = acc2(g3.z, qh[14], uh[14], e0);
  e1 = acc2(g3.w, qh[15], uh[15], e1);
  return e0 + e1;
}

// ---------------------------------------------------------------------------
// Kernel 1: dual GEMM g = h @ W. y==0 -> gl fp16, y==1 -> gr fp32. (unchanged)
// ---------------------------------------------------------------------------
__global__ __launch_bounds__(256) void gemm_dual(
    const float* __restrict__ h, const float* __restrict__ Wl,
    const float* __restrict__ Wr, _Float16* __restrict__ glh,
    float* __restrict__ gr) {
  const int t = threadIdx.x;
  const int row0 = blockIdx.x * 8;
  const float* __restrict__ W = blockIdx.y ? Wr : Wl;

  float acc[8] = {0.f, 0.f, 0.f, 0.f, 0.f, 0.f, 0.f, 0.f};
  const float* Wp = W + t;
  const float* hp = h + (size_t)row0 * FIN;

#pragma unroll 2
  for (int k4 = 0; k4 < FIN / 4; ++k4) {
    float4 hv[8];
#pragma unroll
    for (int r = 0; r < 8; ++r)
      hv[r] = *(const float4*)(hp + r * FIN + 4 * k4);
#pragma unroll
    for (int kk = 0; kk < 4; ++kk) {
      const float w = Wp[(size_t)(4 * k4 + kk) * HF];
#pragma unroll
      for (int r = 0; r < 8; ++r) {
        const float hval = (kk == 0) ? hv[r].x
                         : (kk == 1) ? hv[r].y
                         : (kk == 2) ? hv[r].z : hv[r].w;
        acc[r] = fmaf(hval, w, acc[r]);
      }
    }
  }

  if (blockIdx.y == 0) {
    _Float16* gp = glh + (size_t)row0 * HF + t;
#pragma unroll
    for (int r = 0; r < 8; ++r) gp[(size_t)r * HF] = (_Float16)acc[r];
  } else {
    float* gp = gr + (size_t)row0 * HF + t;
#pragma unroll
    for (int r = 0; r < 8; ++r) gp[(size_t)r * HF] = acc[r];
  }
}

// ---------------------------------------------------------------------------
// Kernel 2: fused GATv2 attention. Block = (head hh, 32-row i-tile, batch b).
// R9: phase 3 = MFMA GEMM C[32x32] = P[32x512] . gr[512x32].
//   - ubuf union: phase<=1 holds gl slice (k-major uint4), phase>=2 holds
//     grT fp16 transposed [n=32][k stride 260 uints] (gl dead after ph.1).
//   - e_s rows (packed fp16 p, k-consecutive) ARE the A-fragments:
//     one ds_read_b128 per K-step (A[m=lane&15][k=quad*8+j], m120 layout).
//   - C/D map col=lane&15,row=quad*4+reg (m89); scale inv_l, store direct.
// ---------------------------------------------------------------------------
__global__ __launch_bounds__(256, 2) void gat_attn(
    const _Float16* __restrict__ glh, const float* __restrict__ gr,
    const int* __restrict__ adj, const float* __restrict__ aw,
    float* __restrict__ out) {
  __shared__ __align__(16) unsigned ubuf[32 * GTS];  // 33.3 KB gl4 / grT union
  __shared__ __align__(16) unsigned e_s[IT][ESTR];   // 34.3 KB fp16 scores->p
  __shared__ float Al_s[NN];                         // 2 KB
  __shared__ float inv_l[IT];

  const int t = threadIdx.x;
  const int hh = blockIdx.x;
  const int i0 = blockIdx.y * IT;
  const int b = blockIdx.z;
  const int ii = t & 31;   // phase-1 query row
  const int jg = t >> 5;   // 0..7, 64 j each

  uint4* gl4 = (uint4*)ubuf;  // [k4][j] = gl4[k4*512 + j], k-major

  const _Float16* glp = glh + (size_t)b * NN * HF + hh * FD;

  // ---- per-thread prep: aw -> wv/uh fp16 pairs; q row -> qh + a_r ----
  h2_t wv[16], uh[16], qh[16];
  float a_r = 0.f;
  {
    const float* qp = gr + (size_t)(b * NN + i0 + ii) * HF + hh * FD;
#pragma unroll
    for (int f4 = 0; f4 < 8; ++f4) {
      const float4 w4 = *(const float4*)(aw + 4 * f4);
      const float4 q4 = *(const float4*)(qp + 4 * f4);
      wv[2 * f4] = pkrtz(CA * w4.x, CA * w4.y);
      wv[2 * f4 + 1] = pkrtz(CA * w4.z, CA * w4.w);
      uh[2 * f4] = pkrtz(CB * w4.x, CB * w4.y);
      uh[2 * f4 + 1] = pkrtz(CB * w4.z, CB * w4.w);
      qh[2 * f4] = pkrtz(q4.x, q4.y);
      qh[2 * f4 + 1] = pkrtz(q4.z, q4.w);
      a_r = fmaf(CA * w4.x, q4.x, a_r);
      a_r = fmaf(CA * w4.y, q4.y, a_r);
      a_r = fmaf(CA * w4.z, q4.z, a_r);
      a_r = fmaf(CA * w4.w, q4.w, a_r);
    }
  }

  // ---- stage gl slice -> LDS (k-major, lane-contiguous writes) + Al ----
#pragma unroll
  for (int c = 0; c < 2; ++c) {
    const int j = t + 256 * c;
    const uint4* gp = (const uint4*)(glp + (size_t)j * HF);
    const uint4 g0 = gp[0], g1 = gp[1], g2 = gp[2], g3 = gp[3];
    gl4[0 * NN + j] = g0;
    gl4[1 * NN + j] = g1;
    gl4[2 * NN + j] = g2;
    gl4[3 * NN + j] = g3;
    float s0 = 0.f, s1 = 0.f;
    H2U v;
#define ALD(gu, i)                                                  \
  v.u = gu.x; s0 = __builtin_amdgcn_fdot2(v.h, wv[i+0], s0, false); \
  v.u = gu.y; s1 = __builtin_amdgcn_fdot2(v.h, wv[i+1], s1, false); \
  v.u = gu.z; s0 = __builtin_amdgcn_fdot2(v.h, wv[i+2], s0, false); \
  v.u = gu.w; s1 = __builtin_amdgcn_fdot2(v.h, wv[i+3], s1, false);
    ALD(g0, 0) ALD(g1, 4) ALD(g2, 8) ALD(g3, 12)
#undef ALD
    Al_s[j] = s0 + s1;
  }
  __syncthreads();

  // ---- phase 1: scores from LDS gl (broadcast b128 reads) ----
  {
    unsigned* erow = &e_s[ii][jg * 32];
    const int* adjp = adj + (size_t)(i0 + ii) * NN + jg * 64;
#pragma unroll 4
    for (int g4 = 0; g4 < 16; ++g4) {
      const int4 a4 = ((const int4*)adjp)[g4];
      const int j = jg * 64 + 4 * g4;
      float e0 = score16(gl4[0 * NN + j], gl4[1 * NN + j], gl4[2 * NN + j],
                         gl4[3 * NN + j], qh, uh, Al_s[j] + a_r);
      float e1 = score16(gl4[0 * NN + j + 1], gl4[1 * NN + j + 1],
                         gl4[2 * NN + j + 1], gl4[3 * NN + j + 1], qh, uh,
                         Al_s[j + 1] + a_r);
      float e2 = score16(gl4[0 * NN + j + 2], gl4[1 * NN + j + 2],
                         gl4[2 * NN + j + 2], gl4[3 * NN + j + 2], qh, uh,
                         Al_s[j + 2] + a_r);
      float e3 = score16(gl4[0 * NN + j + 3], gl4[1 * NN + j + 3],
                         gl4[2 * NN + j + 3], gl4[3 * NN + j + 3], qh, uh,
                         Al_s[j + 3] + a_r);
      e0 = a4.x ? e0 : MASKH;
      e1 = a4.y ? e1 : MASKH;
      e2 = a4.z ? e2 : MASKH;
      e3 = a4.w ? e3 : MASKH;
      erow[2 * g4] = pkrtz_u(e0, e1);
      erow[2 * g4 + 1] = pkrtz_u(e2, e3);
    }
  }
  __syncthreads();

  // ---- phase 2: stage grT (fp16, transposed) into ubuf + row softmax ----
  {
    // staging first so the global loads issue early
    const int fq = t & 7;    // f-quad
    const int jp0 = t >> 3;  // 0..31 (j-pair)
    const float* gbase = gr + (size_t)b * NN * HF + hh * FD + fq * 4;
#pragma unroll
    for (int s2 = 0; s2 < 8; ++s2) {
      const int jp = jp0 + 32 * s2;
      const float4 r0 = *(const float4*)(gbase + (size_t)(2 * jp) * HF);
      const float4 r1 = *(const float4*)(gbase + (size_t)(2 * jp + 1) * HF);
      ubuf[(4 * fq + 0) * GTS + jp] = pkrtz_u(r0.x, r1.x);
      ubuf[(4 * fq + 1) * GTS + jp] = pkrtz_u(r0.y, r1.y);
      ubuf[(4 * fq + 2) * GTS + jp] = pkrtz_u(r0.z, r1.z);
      ubuf[(4 * fq + 3) * GTS + jp] = pkrtz_u(r0.w, r1.w);
    }
    // softmax: 32 rows x 8 lanes
    const int row = t >> 3;
    const int l8 = t & 7;
    unsigned* erow = &e_s[row][0];
    float m = MASKH;
#pragma unroll
    for (int c = 0; c < 32; ++c) {
      H2U v; v.u = erow[l8 + 8 * c];
      m = fmaxf(m, fmaxf((float)v.h.x, (float)v.h.y));
    }
#pragma unroll
    for (int off = 1; off < 8; off <<= 1) m = fmaxf(m, __shfl_xor(m, off));
    float s = 0.f;
#pragma unroll
    for (int c = 0; c < 32; ++c) {
      H2U v; v.u = erow[l8 + 8 * c];
      const float p0 = __expf((float)v.h.x - m);
      const float p1 = __expf((float)v.h.y - m);
      s += p0 + p1;
      erow[l8 + 8 * c] = pkrtz_u(p0, p1);
    }
#pragma unroll
    for (int off = 1; off < 8; off <<= 1) s += __shfl_xor(s, off);
    if (l8 == 0) inv_l[row] = 1.f / s;
  }
  __syncthreads();

  // ---- phase 3: MFMA GEMM  C[32x32] = P . grT^T, one 16x16 tile/wave ----
  {
    const int lane = t & 63;
    const int wv3 = t >> 6;          // 0..3
    const int Mt = wv3 & 1, Nt = wv3 >> 1;
    const int l16 = lane & 15, q = lane >> 4;
    const unsigned* arow = &e_s[Mt * 16 + l16][0];       // A[m][k] packed
    const unsigned* brow = &ubuf[(Nt * 16 + l16) * GTS]; // B[k][n]=grT[n][k]
    v4f acc = {0.f, 0.f, 0.f, 0.f};
#pragma unroll
    for (int s = 0; s < 16; ++s) {
      U8 a; a.u4 = *(const uint4*)(arow + 16 * s + 4 * q);
      U8 bf; bf.u4 = *(const uint4*)(brow + 16 * s + 4 * q);
      acc = __builtin_amdgcn_mfma_f32_16x16x32_f16(a.h, bf.h, acc, 0, 0, 0);
    }
    // epilogue: D[row=q*4+r][col=l16], scale by inv_l, store
    float* op = out + (size_t)(b * NN + i0 + Mt * 16 + q * 4) * HF + hh * FD +
                Nt * 16 + l16;
#pragma unroll
    for (int r = 0; r < 4; ++r) {
      op[(size_t)r * HF] = acc[r] * inv_l[Mt * 16 + q * 4 + r];
    }
  }
}

// ---------------------------------------------------------------------------
extern "C" void kernel_launch(void* const* d_in, const int* in_sizes, int n_in,
                              void* d_out, int out_size, void* d_ws,
                              size_t ws_size, hipStream_t stream) {
  const float* h = (const float*)d_in[0];
  const int* adj = (const int*)d_in[1];
  const float* Wl = (const float*)d_in[2];
  const float* Wr = (const float*)d_in[3];
  const float* aw = (const float*)d_in[4];
  float* out = (float*)d_out;

  _Float16* glh = (_Float16*)d_ws;                              // 1 MB fp16
  float* gr = (float*)((char*)d_ws + (size_t)BB * NN * HF * 2); // 2 MB fp32

  dim3 gg(BB * NN / 8, 2, 1);
  gemm_dual<<<gg, 256, 0, stream>>>(h, Wl, Wr, glh, gr);

  dim3 ga(NH, NN / IT, BB);
  gat_attn<<<ga, 256, 0, stream>>>(glh, gr, adj, aw, out);
}